// Round 6
// baseline (191.751 us; speedup 1.0000x reference)
//
#include <hip/hip_runtime.h>
#include <hip/hip_bf16.h>
#include <math.h>

#define Nn 64
#define Cn 64
#define Tn 64
#define Vn 25
#define Sn 8
#define ICn 8
#define Wn 3
#define WVn 75

typedef __attribute__((ext_vector_type(8))) short s16x8;   // 8 bf16 (4 VGPR)
typedef __attribute__((ext_vector_type(4))) short s16x4;   // 4 bf16 (2 VGPR)
typedef __attribute__((ext_vector_type(4))) float f32x4;   // MFMA acc

#define MFMA16(a, b, c) __builtin_amdgcn_mfma_f32_16x16x32_bf16(a, b, c, 0, 0, 0)

static __device__ inline unsigned short f2bf(float f) {
    __hip_bfloat16 h = __float2bfloat16(f);
    return *reinterpret_cast<unsigned short*>(&h);
}
static __device__ inline float bf2f(unsigned short u) {
    union { unsigned int i; float f; } x;
    x.i = ((unsigned int)u) << 16;
    return x.f;
}

// xs layout: [c][tau2 = tau>>1][128B row of 8x16B chunks]
//   chunk = (((tau&1)<<2) + (v>>3)) ^ (c&7), interior v&7.
#define XSI(c, tau, v) \
    (((c) * 3 + ((tau) >> 1)) * 64 + \
     (((((tau) & 1) << 2) + ((v) >> 3)) ^ ((c) & 7)) * 8 + ((v) & 7))

// ---------------------------------------------------------------------------
// K1: per (n,c) reductions over x rows (collapsed diff/gate branch).
// ---------------------------------------------------------------------------
__global__ __launch_bounds__(64) void k_red(const float* __restrict__ x,
                                            const float* __restrict__ ga,
                                            float* __restrict__ red) {
    const int c = blockIdx.x, n = blockIdx.y;
    const int lane = threadIdx.x;
    float rs = 0.f, r0 = 0.f, r63 = 0.f, xg = 0.f;
    if (lane < Vn) {
        const float* row = x + ((size_t)(n * Cn + c) * Vn + lane) * Tn;
        float g = 0.f;
        for (int j = 0; j < Vn; ++j) g += ga[lane * Vn + j];
        for (int t = 0; t < Tn; ++t) rs += row[t];
        r0 = row[0];
        r63 = row[Tn - 1];
        xg = rs * g;
    }
    for (int off = 32; off > 0; off >>= 1) {
        rs += __shfl_down(rs, off);
        r0 += __shfl_down(r0, off);
        r63 += __shfl_down(r63, off);
        xg += __shfl_down(xg, off);
    }
    if (lane == 0) {
        float* p = red + (size_t)(n * Cn + c) * 4;
        p[0] = rs; p[1] = r0; p[2] = r63; p[3] = xg;
    }
}

// ---------------------------------------------------------------------------
// K1b: gate[n,s,w]
// ---------------------------------------------------------------------------
__global__ __launch_bounds__(64) void k_gate(const float* __restrict__ red,
                                             const float* __restrict__ diff_w,
                                             const float* __restrict__ diff_b,
                                             float* __restrict__ gate) {
    const int n = blockIdx.x;
    const int s = threadIdx.x;
    if (s >= Sn) return;
    float sumd2 = 0.f, rsum = 0.f, rr0 = 0.f, rr63 = 0.f;
    for (int cc = 0; cc < ICn; ++cc) {
        const int oc = s * ICn + cc;
        float a = 0.f;
        for (int c = 0; c < Cn; ++c)
            a += red[(n * Cn + c) * 4 + 3] * diff_w[oc * Cn + c];
        sumd2 += a + 1600.f * diff_b[oc];
        rsum += red[(n * Cn + oc) * 4 + 0];
        rr0  += red[(n * Cn + oc) * 4 + 1];
        rr63 += red[(n * Cn + oc) * 4 + 2];
    }
    const float inv = 1.f / 12800.f;
    float m0 = (sumd2 - (rsum - rr63)) * inv;
    float m1 = (sumd2 - rsum) * inv;
    float m2 = (sumd2 - (rsum - rr0)) * inv;
    float* gp = gate + (n * Sn + s) * Wn;
    gp[0] = 1.f / (1.f + expf(-m0));
    gp[1] = 1.f / (1.f + expf(-m1));
    gp[2] = 1.f / (1.f + expf(-m2));
}

// ---------------------------------------------------------------------------
// K_conv: out_w / ff_w -> bf16
// ---------------------------------------------------------------------------
__global__ __launch_bounds__(256) void k_conv(const float* __restrict__ ow,
                                              const float* __restrict__ fw,
                                              unsigned short* __restrict__ owb,
                                              unsigned short* __restrict__ fwb) {
    int i = blockIdx.x * 256 + threadIdx.x;
    if (i < 64 * 512) owb[i] = f2bf(ow[i]);
    if (i < 64 * 64)  fwb[i] = f2bf(fw[i]);
}

// ---------------------------------------------------------------------------
// K_proj: q/k conv1x1 projections -> bf16 (coalesced along t)
// ---------------------------------------------------------------------------
__global__ __launch_bounds__(256) void k_proj(
    const float* __restrict__ x,
    const float* __restrict__ in_w, const float* __restrict__ in_b,
    const float* __restrict__ inup_w, const float* __restrict__ inup_b,
    __hip_bfloat16* __restrict__ pk, __hip_bfloat16* __restrict__ pq) {
    const int v = blockIdx.x, n = blockIdx.y;
    const int tid = threadIdx.x;
    __shared__ float xs[64 * 65];
    __shared__ float wk[64 * 65];
    __shared__ float wq[64 * 65];

    for (int i = tid; i < 4096; i += 256) {
        int o = i >> 6, c = i & 63;
        wk[o * 65 + c] = in_w[i];
        wq[o * 65 + c] = inup_w[i];
    }
    for (int i = tid; i < 4096; i += 256) {
        int c = i >> 6, t = i & 63;
        xs[c * 65 + t] = x[((size_t)(n * Cn + c) * Vn + v) * Tn + t];
    }
    __syncthreads();

    const int o = tid >> 2, tq = tid & 3;
    float ak[16], aq[16];
#pragma unroll
    for (int t = 0; t < 16; ++t) { ak[t] = 0.f; aq[t] = 0.f; }
    for (int c = 0; c < 64; ++c) {
        float wkc = wk[o * 65 + c], wqc = wq[o * 65 + c];
        const float* xr = &xs[c * 65 + tq * 16];
#pragma unroll
        for (int t = 0; t < 16; ++t) {
            float xv = xr[t];
            ak[t] += wkc * xv;
            aq[t] += wqc * xv;
        }
    }
    const float bk = in_b[o], bq = inup_b[o];
    const size_t base = ((size_t)(n * Cn + o) * Vn + v) * Tn + tq * 16;
#pragma unroll
    for (int t = 0; t < 16; ++t) {
        pk[base + t] = __float2bfloat16(ak[t] + bk);
        pq[base + t] = __float2bfloat16(aq[t] + bq);
    }
}

// ---------------------------------------------------------------------------
// K_att3 (MFMA): fused attention logits + softmax + gate + att0 -> attB.
// Grid swapped to (n, s) so all s-blocks of one n share an XCD (id%8 = n%8).
// ---------------------------------------------------------------------------
__global__ __launch_bounds__(256) void k_att3(
    const __hip_bfloat16* __restrict__ pq, const __hip_bfloat16* __restrict__ pk,
    const float* __restrict__ inup_b, const float* __restrict__ graph,
    const float* __restrict__ att0, const float* __restrict__ gate,
    unsigned short* __restrict__ attB) {
    const int n = blockIdx.x, s = blockIdx.y;
    const int tid = threadIdx.x;
    const int lane = tid & 63, wv = tid >> 6;
    const int r16 = lane & 15, g4 = lane >> 4;

    __shared__ unsigned short QS[25 * 536];
    __shared__ unsigned short KS[32 * 512];
    __shared__ float attL[80 * 33];

    for (int i = tid; i < 2048; i += 256) {
        const int tch = i & 7, cc = (i >> 3) & 7, v = i >> 6;
        if (v < Vn) {
            const s16x8 d = *(const s16x8*)(pk +
                (((size_t)(n * Cn + s * ICn + cc) * Vn + v) * Tn + tch * 8));
#pragma unroll
            for (int j = 0; j < 8; ++j)
                KS[v * 512 + ((((tch * 8 + j)) ^ (v & 7)) << 3) + cc] = ((const unsigned short*)&d)[j];
        } else {
#pragma unroll
            for (int j = 0; j < 8; ++j)
                KS[v * 512 + ((((tch * 8 + j)) ^ (v & 7)) << 3) + cc] = 0;
        }
    }
    for (int i = tid; i < 1600; i += 256) {
        const int tch = i & 7, cc = (i >> 3) & 7, uu = i >> 6;
        const s16x8 d = *(const s16x8*)(pq +
            (((size_t)(n * Cn + s * ICn + cc) * Vn + uu) * Tn + tch * 8));
#pragma unroll
        for (int j = 0; j < 8; ++j)
            QS[uu * 536 + (tch * 8 + j + 1) * 8 + cc] = ((const unsigned short*)&d)[j];
    }
    if (tid < 200) {
        const int uu = tid >> 3, cc = tid & 7;
        const unsigned short b = f2bf(inup_b[s * ICn + cc]);
        QS[uu * 536 + 0 * 8 + cc] = b;
        QS[uu * 536 + 65 * 8 + cc] = b;
    }
    __syncthreads();

    for (int tile = wv; tile < 10; tile += 4) {
        const int mt = tile >> 1, nt = tile & 1;
        const int u = mt * 16 + r16;
        const int w = u / 25, uu = u % 25;
        const int v = nt * 16 + r16;
        const unsigned short* qbase = &QS[uu * 536 + (g4 + w) * 8];
        const unsigned short* kbase = &KS[v * 512];
        f32x4 acc = (f32x4){0.f, 0.f, 0.f, 0.f};
#pragma unroll
        for (int kb = 0; kb < 16; ++kb) {
            const s16x8 af = *(const s16x8*)(qbase + kb * 32);
            const s16x8 bf = *(const s16x8*)(kbase + (((kb * 4 + g4) ^ (v & 7)) << 3));
            acc = MFMA16(af, bf, acc);
        }
#pragma unroll
        for (int r = 0; r < 4; ++r)
            attL[(mt * 16 + g4 * 4 + r) * 33 + v] = acc[r];
    }
    __syncthreads();

    if (tid < WVn) {
        const int u = tid, u0 = u % Vn;
        const float* gr = graph + (s * Vn + u0) * Vn;
        float av[Vn];
        float mx = -1e30f;
#pragma unroll
        for (int v = 0; v < Vn; ++v) {
            float a = attL[u * 33 + v] * (1.f / 512.f);
            av[v] = (gr[v] > 0.f) ? a : -1e30f;
            mx = fmaxf(mx, av[v]);
        }
        float ssum = 0.f;
#pragma unroll
        for (int v = 0; v < Vn; ++v) {
            float e = (av[v] > -1e29f) ? expf(av[v] - mx) : 0.f;
            av[v] = e;
            ssum += e;
        }
        const float g = gate[(n * Sn + s) * Wn + (u % Wn)];
        const float sc = g / ssum;
        const float* a0 = att0 + (s * WVn + u) * Vn;
#pragma unroll
        for (int v = 0; v < Vn; ++v) attL[u * 33 + v] = av[v] * sc + a0[v];
    }
    __syncthreads();

    unsigned short* ab = attB + ((size_t)(n * Sn + s)) * 32 * 96;
    for (int i = tid; i < 32 * 96; i += 256) {
        const int v = i / 96, kk = i % 96;
        const int w2 = kk >> 5, vp = kk & 31;
        float val = (v < Vn && vp < Vn) ? attL[(w2 * Vn + vp) * 33 + v] : 0.f;
        ab[i] = f2bf(val);
    }
}

// ---------------------------------------------------------------------------
// K_main5 (MFMA, barrier-free, t-chunk 4, 3 blocks/CU): per (n, tc) block,
// 4 waves; wave wv owns t = tc*4 + wv. Chain stage1 -> stage2 -> epi1 ->
// ff -> epi2 is wave-private through a per-wave yw slab (no __syncthreads
// in the s-loop; 1 barrier total).
//   xs: [c][tau2][128B row], 16B-chunk XOR by (c&7)  -> 2-way banked reads.
//   yw: [col=v(32)][c(64)], 16B-chunk XOR by (col&7) -> 2-way.
// Grid (n, tc): all 16 tc-blocks of one n land on one XCD (id%8 = n%8).
// ---------------------------------------------------------------------------
__global__ __launch_bounds__(256, 3) void k_main5(
    const float* __restrict__ x, const unsigned short* __restrict__ attB,
    const unsigned short* __restrict__ out_wbf, const float* __restrict__ out_b,
    const float* __restrict__ og, const float* __restrict__ obeta,
    const float* __restrict__ orm, const float* __restrict__ orv,
    const unsigned short* __restrict__ ff_wbf, const float* __restrict__ ff_b,
    const float* __restrict__ fg, const float* __restrict__ fbeta,
    const float* __restrict__ frm, const float* __restrict__ frv,
    float* __restrict__ out) {
    const int n = blockIdx.x, tc = blockIdx.y;
    const int t0 = tc * 4;
    const int tid = threadIdx.x;
    const int lane = tid & 63, wv = tid >> 6;
    const int r16 = lane & 15, g4 = lane >> 4;

    __shared__ unsigned short xs[64 * 3 * 64];   // 24 KB
    __shared__ unsigned short yw[4 * 32 * 64];   // 16 KB (per-wave 4 KB slabs)
    __shared__ float bnp[384];

    if (tid < 64) {
        int o = tid;
        float so = og[o] * rsqrtf(orv[o] + 1e-5f);
        bnp[o] = so; bnp[64 + o] = obeta[o] - orm[o] * so; bnp[128 + o] = out_b[o];
        float sf = fg[o] * rsqrtf(frv[o] + 1e-5f);
        bnp[192 + o] = sf; bnp[256 + o] = fbeta[o] - frm[o] * sf; bnp[320 + o] = ff_b[o];
    }
    // stage x window: tau 0..5 <-> global t = t0-1+tau; OOB t/v -> 0
    for (int p = tid; p < 64 * 32; p += 256) {
        int c = p >> 5, v = p & 31;
        const float* xr = x + ((size_t)(n * Cn + c) * Vn + (v < Vn ? v : 0)) * Tn;
#pragma unroll
        for (int tau = 0; tau < 6; ++tau) {
            int tg = t0 - 1 + tau;
            float val = (v < Vn && tg >= 0 && tg < Tn) ? xr[tg] : 0.f;
            xs[XSI(c, tau, v)] = f2bf(val);
        }
    }
    __syncthreads();   // the ONLY barrier

    unsigned short* myw = yw + wv * (32 * 64);

    f32x4 accO[4][2];
#pragma unroll
    for (int i = 0; i < 4; ++i)
#pragma unroll
        for (int j = 0; j < 2; ++j) accO[i][j] = (f32x4){0.f, 0.f, 0.f, 0.f};

    for (int s = 0; s < Sn; ++s) {
        // ---- stage1: y2[c][v] at this wave's t (= t0 + wv)
        const unsigned short* aB = attB + ((size_t)(n * Sn + s)) * 32 * 96;
        s16x8 bfr[3][2];
#pragma unroll
        for (int k = 0; k < 3; ++k)
#pragma unroll
            for (int nt = 0; nt < 2; ++nt)
                bfr[k][nt] = *(const s16x8*)(aB + (nt * 16 + r16) * 96 + k * 32 + g4 * 8);
#pragma unroll
        for (int m = 0; m < 4; ++m) {
            const int ca = m * 16 + r16;
            f32x4 c0 = (f32x4){0.f, 0.f, 0.f, 0.f};
            f32x4 c1 = (f32x4){0.f, 0.f, 0.f, 0.f};
#pragma unroll
            for (int kb = 0; kb < 3; ++kb) {
                const int tau = wv + kb;
                const s16x8 af = *(const s16x8*)&xs[
                    (ca * 3 + (tau >> 1)) * 64 +
                    (((((tau & 1) << 2) + g4) ^ (ca & 7)) << 3)];
                c0 = MFMA16(af, bfr[kb][0], c0);
                c1 = MFMA16(af, bfr[kb][1], c1);
            }
            const int cw = m * 16 + g4 * 4;   // 4 consecutive c (cw&7 in {0,4})
            const int chunkbase = cw >> 3;
            s16x4 p0, p1;
#pragma unroll
            for (int r = 0; r < 4; ++r) { p0[r] = f2bf(c0[r]); p1[r] = f2bf(c1[r]); }
            const int col0 = r16, col1 = 16 + r16;
            *(s16x4*)&myw[col0 * 64 + ((chunkbase ^ (col0 & 7)) << 3) + (cw & 7)] = p0;
            *(s16x4*)&myw[col1 * 64 + ((chunkbase ^ (col1 & 7)) << 3) + (cw & 7)] = p1;
        }
        // ---- stage2: accO[o][col] += out_w[o, s*64+c] * y2 (wave-private)
        s16x8 wa[4][2];
#pragma unroll
        for (int ma = 0; ma < 4; ++ma)
#pragma unroll
            for (int kb = 0; kb < 2; ++kb)
                wa[ma][kb] = *(const s16x8*)(out_wbf +
                    (size_t)(ma * 16 + r16) * 512 + s * 64 + kb * 32 + g4 * 8);
#pragma unroll
        for (int na = 0; na < 2; ++na) {
            const int col = na * 16 + r16;
            const s16x8 b0 = *(const s16x8*)&myw[col * 64 + (((g4) ^ (col & 7)) << 3)];
            const s16x8 b1 = *(const s16x8*)&myw[col * 64 + (((4 + g4) ^ (col & 7)) << 3)];
#pragma unroll
            for (int ma = 0; ma < 4; ++ma) {
                accO[ma][na] = MFMA16(wa[ma][0], b0, accO[ma][na]);
                accO[ma][na] = MFMA16(wa[ma][1], b1, accO[ma][na]);
            }
        }
    }

    // ---- epilogue1: y1 = leaky(x + BN(accO)) -> myw[col][o], cache xv
    s16x4 xc[4][2];
#pragma unroll
    for (int ma = 0; ma < 4; ++ma) {
#pragma unroll
        for (int na = 0; na < 2; ++na) {
            const int col = na * 16 + r16;   // col == v
            const int ob = ma * 16 + g4 * 4;
            s16x4 p;
#pragma unroll
            for (int r = 0; r < 4; ++r) {
                const int o = ob + r;
                const unsigned short xu = xs[XSI(o, wv + 1, col)];
                xc[ma][na][r] = (short)xu;
                float xv = bf2f(xu);
                float val = (accO[ma][na][r] + bnp[128 + o]) * bnp[o] + bnp[64 + o];
                float y1 = xv + val;
                y1 = (y1 > 0.f) ? y1 : 0.1f * y1;
                p[r] = f2bf(y1);
            }
            *(s16x4*)&myw[col * 64 + (((ob >> 3) ^ (col & 7)) << 3) + (ob & 7)] = p;
        }
    }
    // ---- ff (wave-private): accF[o'][col] = ff_w[o'][o] * y1
    f32x4 accF[4][2];
#pragma unroll
    for (int i = 0; i < 4; ++i)
#pragma unroll
        for (int j = 0; j < 2; ++j) accF[i][j] = (f32x4){0.f, 0.f, 0.f, 0.f};
    s16x8 fa[4][2];
#pragma unroll
    for (int ma = 0; ma < 4; ++ma)
#pragma unroll
        for (int kb = 0; kb < 2; ++kb)
            fa[ma][kb] = *(const s16x8*)(ff_wbf +
                (size_t)(ma * 16 + r16) * 64 + kb * 32 + g4 * 8);
#pragma unroll
    for (int na = 0; na < 2; ++na) {
        const int col = na * 16 + r16;
        const s16x8 b0 = *(const s16x8*)&myw[col * 64 + (((g4) ^ (col & 7)) << 3)];
        const s16x8 b1 = *(const s16x8*)&myw[col * 64 + (((4 + g4) ^ (col & 7)) << 3)];
#pragma unroll
        for (int ma = 0; ma < 4; ++ma) {
            accF[ma][na] = MFMA16(fa[ma][0], b0, accF[ma][na]);
            accF[ma][na] = MFMA16(fa[ma][1], b1, accF[ma][na]);
        }
    }
    // ---- epilogue2 + store
    const int tt = t0 + wv;
#pragma unroll
    for (int ma = 0; ma < 4; ++ma) {
#pragma unroll
        for (int na = 0; na < 2; ++na) {
            const int v = na * 16 + r16;
            if (v < Vn) {
                const int ob = ma * 16 + g4 * 4;
#pragma unroll
                for (int r = 0; r < 4; ++r) {
                    const int o = ob + r;
                    const float xv = bf2f((unsigned short)xc[ma][na][r]);
                    float val = (accF[ma][na][r] + bnp[320 + o]) * bnp[192 + o] + bnp[256 + o];
                    float y2v = xv + val;
                    y2v = (y2v > 0.f) ? y2v : 0.1f * y2v;
                    float outv = y2v + xv;
                    outv = (outv > 0.f) ? outv : 0.f;
                    out[((size_t)(n * Cn + o) * Vn + v) * Tn + tt] = outv;
                }
            }
        }
    }
}

// ---------------------------------------------------------------------------
extern "C" void kernel_launch(void* const* d_in, const int* in_sizes, int n_in,
                              void* d_out, int out_size, void* d_ws, size_t ws_size,
                              hipStream_t stream) {
    const float* x       = (const float*)d_in[0];
    const float* graph   = (const float*)d_in[1];
    const float* graph_a = (const float*)d_in[2];
    const float* in_w    = (const float*)d_in[3];
    const float* in_b    = (const float*)d_in[4];
    const float* inup_w  = (const float*)d_in[5];
    const float* inup_b  = (const float*)d_in[6];
    const float* diff_w  = (const float*)d_in[7];
    const float* diff_b  = (const float*)d_in[8];
    const float* att0    = (const float*)d_in[9];
    const float* out_w   = (const float*)d_in[10];
    const float* out_b   = (const float*)d_in[11];
    const float* og      = (const float*)d_in[12];
    const float* obeta   = (const float*)d_in[13];
    const float* orm     = (const float*)d_in[14];
    const float* orv     = (const float*)d_in[15];
    const float* ff_w    = (const float*)d_in[16];
    const float* ff_b    = (const float*)d_in[17];
    const float* fg      = (const float*)d_in[18];
    const float* fbeta   = (const float*)d_in[19];
    const float* frm     = (const float*)d_in[20];
    const float* frv     = (const float*)d_in[21];
    float* out = (float*)d_out;

    // ws layout (bytes): red@0 (64K) | gate@65,536 | attB@71,680 (3M)
    //   out_wbf@3,217,408 | ff_wbf@3,282,944 | pq@3,291,136 | pk@16,398,336
    char* wsb = (char*)d_ws;
    float* red_ws  = (float*)(wsb);
    float* gate_ws = (float*)(wsb + 65536);
    unsigned short* attB = (unsigned short*)(wsb + 71680);
    unsigned short* owb  = (unsigned short*)(wsb + 3217408);
    unsigned short* fwb  = (unsigned short*)(wsb + 3282944);
    __hip_bfloat16* pq = (__hip_bfloat16*)(wsb + 3291136);
    __hip_bfloat16* pk = (__hip_bfloat16*)(wsb + 16398336);

    k_red<<<dim3(Cn, Nn), 64, 0, stream>>>(x, graph_a, red_ws);
    k_gate<<<dim3(Nn), 64, 0, stream>>>(red_ws, diff_w, diff_b, gate_ws);
    k_conv<<<dim3(128), 256, 0, stream>>>(out_w, ff_w, owb, fwb);
    k_proj<<<dim3(Vn, Nn), 256, 0, stream>>>(x, in_w, in_b, inup_w, inup_b, pk, pq);
    k_att3<<<dim3(Nn, Sn), 256, 0, stream>>>(pq, pk, inup_b, graph, att0, gate_ws, attB);
    k_main5<<<dim3(Nn, Tn / 4), 256, 0, stream>>>(x, attB, owb, out_b, og, obeta,
                                                  orm, orv, fwb, ff_b, fg, fbeta,
                                                  frm, frv, out);
}

// Round 7
// 176.679 us; speedup vs baseline: 1.0853x; 1.0853x over previous
//
#include <hip/hip_runtime.h>
#include <hip/hip_bf16.h>
#include <math.h>

#define Nn 64
#define Cn 64
#define Tn 64
#define Vn 25
#define Sn 8
#define ICn 8
#define Wn 3
#define WVn 75

typedef __attribute__((ext_vector_type(8))) short s16x8;   // 8 bf16 (4 VGPR)
typedef __attribute__((ext_vector_type(4))) short s16x4;   // 4 bf16 (2 VGPR)
typedef __attribute__((ext_vector_type(4))) float f32x4;   // MFMA acc

#define MFMA16(a, b, c) __builtin_amdgcn_mfma_f32_16x16x32_bf16(a, b, c, 0, 0, 0)

static __device__ inline unsigned short f2bf(float f) {
    __hip_bfloat16 h = __float2bfloat16(f);
    return *reinterpret_cast<unsigned short*>(&h);
}
static __device__ inline float bf2f(unsigned short u) {
    union { unsigned int i; float f; } x;
    x.i = ((unsigned int)u) << 16;
    return x.f;
}

// xs layout: [c][tau2 = tau>>1][128B row of 8x16B chunks]
//   chunk = (((tau&1)<<2) + (v>>3)) ^ (c&7), interior v&7.
#define XSI(c, tau, v) \
    (((c) * 3 + ((tau) >> 1)) * 64 + \
     (((((tau) & 1) << 2) + ((v) >> 3)) ^ ((c) & 7)) * 8 + ((v) & 7))

// ---------------------------------------------------------------------------
// K1: per (n,c) reductions over x rows (collapsed diff/gate branch).
// ---------------------------------------------------------------------------
__global__ __launch_bounds__(64) void k_red(const float* __restrict__ x,
                                            const float* __restrict__ ga,
                                            float* __restrict__ red) {
    const int c = blockIdx.x, n = blockIdx.y;
    const int lane = threadIdx.x;
    float rs = 0.f, r0 = 0.f, r63 = 0.f, xg = 0.f;
    if (lane < Vn) {
        const float* row = x + ((size_t)(n * Cn + c) * Vn + lane) * Tn;
        float g = 0.f;
        for (int j = 0; j < Vn; ++j) g += ga[lane * Vn + j];
        for (int t = 0; t < Tn; ++t) rs += row[t];
        r0 = row[0];
        r63 = row[Tn - 1];
        xg = rs * g;
    }
    for (int off = 32; off > 0; off >>= 1) {
        rs += __shfl_down(rs, off);
        r0 += __shfl_down(r0, off);
        r63 += __shfl_down(r63, off);
        xg += __shfl_down(xg, off);
    }
    if (lane == 0) {
        float* p = red + (size_t)(n * Cn + c) * 4;
        p[0] = rs; p[1] = r0; p[2] = r63; p[3] = xg;
    }
}

// ---------------------------------------------------------------------------
// K1b: gate[n,s,w]
// ---------------------------------------------------------------------------
__global__ __launch_bounds__(64) void k_gate(const float* __restrict__ red,
                                             const float* __restrict__ diff_w,
                                             const float* __restrict__ diff_b,
                                             float* __restrict__ gate) {
    const int n = blockIdx.x;
    const int s = threadIdx.x;
    if (s >= Sn) return;
    float sumd2 = 0.f, rsum = 0.f, rr0 = 0.f, rr63 = 0.f;
    for (int cc = 0; cc < ICn; ++cc) {
        const int oc = s * ICn + cc;
        float a = 0.f;
        for (int c = 0; c < Cn; ++c)
            a += red[(n * Cn + c) * 4 + 3] * diff_w[oc * Cn + c];
        sumd2 += a + 1600.f * diff_b[oc];
        rsum += red[(n * Cn + oc) * 4 + 0];
        rr0  += red[(n * Cn + oc) * 4 + 1];
        rr63 += red[(n * Cn + oc) * 4 + 2];
    }
    const float inv = 1.f / 12800.f;
    float m0 = (sumd2 - (rsum - rr63)) * inv;
    float m1 = (sumd2 - rsum) * inv;
    float m2 = (sumd2 - (rsum - rr0)) * inv;
    float* gp = gate + (n * Sn + s) * Wn;
    gp[0] = 1.f / (1.f + expf(-m0));
    gp[1] = 1.f / (1.f + expf(-m1));
    gp[2] = 1.f / (1.f + expf(-m2));
}

// ---------------------------------------------------------------------------
// K_conv: out_w / ff_w -> bf16
// ---------------------------------------------------------------------------
__global__ __launch_bounds__(256) void k_conv(const float* __restrict__ ow,
                                              const float* __restrict__ fw,
                                              unsigned short* __restrict__ owb,
                                              unsigned short* __restrict__ fwb) {
    int i = blockIdx.x * 256 + threadIdx.x;
    if (i < 64 * 512) owb[i] = f2bf(ow[i]);
    if (i < 64 * 64)  fwb[i] = f2bf(fw[i]);
}

// ---------------------------------------------------------------------------
// K_proj: q/k conv1x1 projections -> bf16, TRANSPOSED layout [n][v][t][o]
// (o fastest -> coalesced 128B stores; feeds k_att3's b128 staging directly).
// Thread map: lane = o (64), tq = tid>>6 (4 chunks of 16 t).
// ---------------------------------------------------------------------------
__global__ __launch_bounds__(256) void k_proj(
    const float* __restrict__ x,
    const float* __restrict__ in_w, const float* __restrict__ in_b,
    const float* __restrict__ inup_w, const float* __restrict__ inup_b,
    unsigned short* __restrict__ pk, unsigned short* __restrict__ pq) {
    const int v = blockIdx.x, n = blockIdx.y;
    const int tid = threadIdx.x;
    __shared__ float xs[64 * 65];   // [c][t]
    __shared__ float wk[64 * 65];   // [o][c]
    __shared__ float wq[64 * 65];

    for (int i = tid; i < 4096; i += 256) {
        int o = i >> 6, c = i & 63;
        wk[o * 65 + c] = in_w[i];
        wq[o * 65 + c] = inup_w[i];
    }
    for (int i = tid; i < 4096; i += 256) {
        int c = i >> 6, t = i & 63;
        xs[c * 65 + t] = x[((size_t)(n * Cn + c) * Vn + v) * Tn + t];
    }
    __syncthreads();

    const int o = tid & 63, tq = tid >> 6;   // wave-uniform tq
    float ak[16], aq[16];
#pragma unroll
    for (int t = 0; t < 16; ++t) { ak[t] = 0.f; aq[t] = 0.f; }
    for (int c = 0; c < 64; ++c) {
        float wkc = wk[o * 65 + c], wqc = wq[o * 65 + c];
        const float* xr = &xs[c * 65 + tq * 16];   // uniform address
#pragma unroll
        for (int t = 0; t < 16; ++t) {
            float xv = xr[t];
            ak[t] += wkc * xv;
            aq[t] += wqc * xv;
        }
    }
    const float bk = in_b[o], bq = inup_b[o];
    const size_t base = ((size_t)(n * Vn + v) * Tn + tq * 16) * 64 + o;
#pragma unroll
    for (int t = 0; t < 16; ++t) {
        pk[base + t * 64] = f2bf(ak[t] + bk);
        pq[base + t * 64] = f2bf(aq[t] + bq);
    }
}

// ---------------------------------------------------------------------------
// K_att3 (MFMA): fused attention logits + softmax + gate + att0 -> attB.
// pq/pk layout [n][v][t][o]: staging = 1 b128 load + 1 b128 ds_write per
// (v,t) (was 1 load + 8 scalar b16 writes).
// ---------------------------------------------------------------------------
__global__ __launch_bounds__(256) void k_att3(
    const unsigned short* __restrict__ pq, const unsigned short* __restrict__ pk,
    const float* __restrict__ inup_b, const float* __restrict__ graph,
    const float* __restrict__ att0, const float* __restrict__ gate,
    unsigned short* __restrict__ attB) {
    const int n = blockIdx.x, s = blockIdx.y;
    const int tid = threadIdx.x;
    const int lane = tid & 63, wv = tid >> 6;
    const int r16 = lane & 15, g4 = lane >> 4;

    __shared__ unsigned short QS[25 * 536];   // [uu][slot 0..66][cc]
    __shared__ unsigned short KS[32 * 512];   // [v][(t^(v&7))*8+cc]
    __shared__ float attL[80 * 33];

    // ---- stage K: one b128 per (v,t); v>=25 rows zero
    for (int i = tid; i < 2048; i += 256) {
        const int t = i & 63, v = i >> 6;
        s16x8 d = (s16x8){0, 0, 0, 0, 0, 0, 0, 0};
        if (v < Vn)
            d = *(const s16x8*)(pk + (((size_t)(n * Vn + v) * Tn + t) << 6) + s * ICn);
        *(s16x8*)&KS[v * 512 + ((t ^ (v & 7)) << 3)] = d;
    }
    // ---- stage Q: one b128 per (uu,t); slot = t+1
    for (int i = tid; i < 1600; i += 256) {
        const int t = i & 63, uu = i >> 6;
        const s16x8 d = *(const s16x8*)(pq +
            (((size_t)(n * Vn + uu) * Tn + t) << 6) + s * ICn);
        *(s16x8*)&QS[uu * 536 + (t + 1) * 8] = d;
    }
    if (tid < 50) {  // bias edge slots 0 and 65
        const int uu = tid >> 1, slot = (tid & 1) * 65;
#pragma unroll
        for (int cc = 0; cc < ICn; ++cc)
            QS[uu * 536 + slot * 8 + cc] = f2bf(inup_b[s * ICn + cc]);
    }
    __syncthreads();

    for (int tile = wv; tile < 10; tile += 4) {
        const int mt = tile >> 1, nt = tile & 1;
        const int u = mt * 16 + r16;
        const int w = u / 25, uu = u % 25;
        const int v = nt * 16 + r16;
        const unsigned short* qbase = &QS[uu * 536 + (g4 + w) * 8];
        const unsigned short* kbase = &KS[v * 512];
        f32x4 acc = (f32x4){0.f, 0.f, 0.f, 0.f};
#pragma unroll
        for (int kb = 0; kb < 16; ++kb) {
            const s16x8 af = *(const s16x8*)(qbase + kb * 32);
            const s16x8 bf = *(const s16x8*)(kbase + (((kb * 4 + g4) ^ (v & 7)) << 3));
            acc = MFMA16(af, bf, acc);
        }
#pragma unroll
        for (int r = 0; r < 4; ++r)
            attL[(mt * 16 + g4 * 4 + r) * 33 + v] = acc[r];
    }
    __syncthreads();

    if (tid < WVn) {
        const int u = tid, u0 = u % Vn;
        const float* gr = graph + (s * Vn + u0) * Vn;
        float av[Vn];
        float mx = -1e30f;
#pragma unroll
        for (int v = 0; v < Vn; ++v) {
            float a = attL[u * 33 + v] * (1.f / 512.f);
            av[v] = (gr[v] > 0.f) ? a : -1e30f;
            mx = fmaxf(mx, av[v]);
        }
        float ssum = 0.f;
#pragma unroll
        for (int v = 0; v < Vn; ++v) {
            float e = (av[v] > -1e29f) ? expf(av[v] - mx) : 0.f;
            av[v] = e;
            ssum += e;
        }
        const float g = gate[(n * Sn + s) * Wn + (u % Wn)];
        const float sc = g / ssum;
        const float* a0 = att0 + (s * WVn + u) * Vn;
#pragma unroll
        for (int v = 0; v < Vn; ++v) attL[u * 33 + v] = av[v] * sc + a0[v];
    }
    __syncthreads();

    unsigned short* ab = attB + ((size_t)(n * Sn + s)) * 32 * 96;
    for (int i = tid; i < 32 * 96; i += 256) {
        const int v = i / 96, kk = i % 96;
        const int w2 = kk >> 5, vp = kk & 31;
        float val = (v < Vn && vp < Vn) ? attL[(w2 * Vn + vp) * 33 + v] : 0.f;
        ab[i] = f2bf(val);
    }
}

// ---------------------------------------------------------------------------
// K_main6 (MFMA, barrier-free, latency-trimmed s-loop): per (n, tc) block,
// 4 waves; wave wv owns t = tc*4 + wv.
// Changes vs k_main5: (1) the 12 loop-invariant xs A-frags are hoisted into
// registers before the s-loop (loaded ONCE, removes 84 dependent LDS reads
// from the chain); (2) wa/bfr global loads issue at iteration top so the
// fully-unrolled scheduler can hoist them across iterations; (3) setprio(1)
// around MFMA clusters (independent waves -> scheduler arbitration pays).
// ---------------------------------------------------------------------------
__global__ __launch_bounds__(256, 3) void k_main6(
    const float* __restrict__ x, const unsigned short* __restrict__ attB,
    const unsigned short* __restrict__ out_wbf, const float* __restrict__ out_b,
    const float* __restrict__ og, const float* __restrict__ obeta,
    const float* __restrict__ orm, const float* __restrict__ orv,
    const unsigned short* __restrict__ ff_wbf, const float* __restrict__ ff_b,
    const float* __restrict__ fg, const float* __restrict__ fbeta,
    const float* __restrict__ frm, const float* __restrict__ frv,
    float* __restrict__ out) {
    const int n = blockIdx.x, tc = blockIdx.y;
    const int t0 = tc * 4;
    const int tid = threadIdx.x;
    const int lane = tid & 63, wv = tid >> 6;
    const int r16 = lane & 15, g4 = lane >> 4;

    __shared__ unsigned short xs[64 * 3 * 64];   // 24 KB
    __shared__ unsigned short yw[4 * 32 * 64];   // 16 KB (per-wave 4 KB slabs)
    __shared__ float bnp[384];

    if (tid < 64) {
        int o = tid;
        float so = og[o] * rsqrtf(orv[o] + 1e-5f);
        bnp[o] = so; bnp[64 + o] = obeta[o] - orm[o] * so; bnp[128 + o] = out_b[o];
        float sf = fg[o] * rsqrtf(frv[o] + 1e-5f);
        bnp[192 + o] = sf; bnp[256 + o] = fbeta[o] - frm[o] * sf; bnp[320 + o] = ff_b[o];
    }
    for (int p = tid; p < 64 * 32; p += 256) {
        int c = p >> 5, v = p & 31;
        const float* xr = x + ((size_t)(n * Cn + c) * Vn + (v < Vn ? v : 0)) * Tn;
#pragma unroll
        for (int tau = 0; tau < 6; ++tau) {
            int tg = t0 - 1 + tau;
            float val = (v < Vn && tg >= 0 && tg < Tn) ? xr[tg] : 0.f;
            xs[XSI(c, tau, v)] = f2bf(val);
        }
    }
    __syncthreads();   // the ONLY barrier

    unsigned short* myw = yw + wv * (32 * 64);

    // ---- hoisted, loop-invariant A-frags (upf window for this wave's t)
    s16x8 af[4][3];
#pragma unroll
    for (int m = 0; m < 4; ++m) {
        const int ca = m * 16 + r16;
#pragma unroll
        for (int kb = 0; kb < 3; ++kb) {
            const int tau = wv + kb;
            af[m][kb] = *(const s16x8*)&xs[
                (ca * 3 + (tau >> 1)) * 64 +
                (((((tau & 1) << 2) + g4) ^ (ca & 7)) << 3)];
        }
    }

    f32x4 accO[4][2];
#pragma unroll
    for (int i = 0; i < 4; ++i)
#pragma unroll
        for (int j = 0; j < 2; ++j) accO[i][j] = (f32x4){0.f, 0.f, 0.f, 0.f};

#pragma unroll
    for (int s = 0; s < Sn; ++s) {
        // ---- issue global loads first (stage2 weights + stage1 attB frags)
        s16x8 wa[4][2];
#pragma unroll
        for (int ma = 0; ma < 4; ++ma)
#pragma unroll
            for (int kb = 0; kb < 2; ++kb)
                wa[ma][kb] = *(const s16x8*)(out_wbf +
                    (size_t)(ma * 16 + r16) * 512 + s * 64 + kb * 32 + g4 * 8);
        const unsigned short* aB = attB + ((size_t)(n * Sn + s)) * 32 * 96;
        s16x8 bfr[3][2];
#pragma unroll
        for (int k = 0; k < 3; ++k)
#pragma unroll
            for (int nt = 0; nt < 2; ++nt)
                bfr[k][nt] = *(const s16x8*)(aB + (nt * 16 + r16) * 96 + k * 32 + g4 * 8);

        // ---- stage1: y2[c][v] at this wave's t (A-frags from registers)
        __builtin_amdgcn_s_setprio(1);
#pragma unroll
        for (int m = 0; m < 4; ++m) {
            f32x4 c0 = (f32x4){0.f, 0.f, 0.f, 0.f};
            f32x4 c1 = (f32x4){0.f, 0.f, 0.f, 0.f};
#pragma unroll
            for (int kb = 0; kb < 3; ++kb) {
                c0 = MFMA16(af[m][kb], bfr[kb][0], c0);
                c1 = MFMA16(af[m][kb], bfr[kb][1], c1);
            }
            __builtin_amdgcn_s_setprio(0);
            const int cw = m * 16 + g4 * 4;
            const int chunkbase = cw >> 3;
            s16x4 p0, p1;
#pragma unroll
            for (int r = 0; r < 4; ++r) { p0[r] = f2bf(c0[r]); p1[r] = f2bf(c1[r]); }
            const int col0 = r16, col1 = 16 + r16;
            *(s16x4*)&myw[col0 * 64 + ((chunkbase ^ (col0 & 7)) << 3) + (cw & 7)] = p0;
            *(s16x4*)&myw[col1 * 64 + ((chunkbase ^ (col1 & 7)) << 3) + (cw & 7)] = p1;
            __builtin_amdgcn_s_setprio(1);
        }
        __builtin_amdgcn_s_setprio(0);

        // ---- stage2: accO[o][col] += out_w[o, s*64+c] * y2 (wave-private)
#pragma unroll
        for (int na = 0; na < 2; ++na) {
            const int col = na * 16 + r16;
            const s16x8 b0 = *(const s16x8*)&myw[col * 64 + (((g4) ^ (col & 7)) << 3)];
            const s16x8 b1 = *(const s16x8*)&myw[col * 64 + (((4 + g4) ^ (col & 7)) << 3)];
            __builtin_amdgcn_s_setprio(1);
#pragma unroll
            for (int ma = 0; ma < 4; ++ma) {
                accO[ma][na] = MFMA16(wa[ma][0], b0, accO[ma][na]);
                accO[ma][na] = MFMA16(wa[ma][1], b1, accO[ma][na]);
            }
            __builtin_amdgcn_s_setprio(0);
        }
    }

    // ---- epilogue1: y1 = leaky(x + BN(accO)) -> myw[col][o], cache xv
    s16x4 xc[4][2];
#pragma unroll
    for (int ma = 0; ma < 4; ++ma) {
#pragma unroll
        for (int na = 0; na < 2; ++na) {
            const int col = na * 16 + r16;   // col == v
            const int ob = ma * 16 + g4 * 4;
            s16x4 p;
#pragma unroll
            for (int r = 0; r < 4; ++r) {
                const int o = ob + r;
                const unsigned short xu = xs[XSI(o, wv + 1, col)];
                xc[ma][na][r] = (short)xu;
                float xv = bf2f(xu);
                float val = (accO[ma][na][r] + bnp[128 + o]) * bnp[o] + bnp[64 + o];
                float y1 = xv + val;
                y1 = (y1 > 0.f) ? y1 : 0.1f * y1;
                p[r] = f2bf(y1);
            }
            *(s16x4*)&myw[col * 64 + (((ob >> 3) ^ (col & 7)) << 3) + (ob & 7)] = p;
        }
    }
    // ---- ff (wave-private): accF[o'][col] = ff_w[o'][o] * y1
    f32x4 accF[4][2];
#pragma unroll
    for (int i = 0; i < 4; ++i)
#pragma unroll
        for (int j = 0; j < 2; ++j) accF[i][j] = (f32x4){0.f, 0.f, 0.f, 0.f};
    s16x8 fa[4][2];
#pragma unroll
    for (int ma = 0; ma < 4; ++ma)
#pragma unroll
        for (int kb = 0; kb < 2; ++kb)
            fa[ma][kb] = *(const s16x8*)(ff_wbf +
                (size_t)(ma * 16 + r16) * 64 + kb * 32 + g4 * 8);
#pragma unroll
    for (int na = 0; na < 2; ++na) {
        const int col = na * 16 + r16;
        const s16x8 b0 = *(const s16x8*)&myw[col * 64 + (((g4) ^ (col & 7)) << 3)];
        const s16x8 b1 = *(const s16x8*)&myw[col * 64 + (((4 + g4) ^ (col & 7)) << 3)];
#pragma unroll
        for (int ma = 0; ma < 4; ++ma) {
            accF[ma][na] = MFMA16(fa[ma][0], b0, accF[ma][na]);
            accF[ma][na] = MFMA16(fa[ma][1], b1, accF[ma][na]);
        }
    }
    // ---- epilogue2 + store
    const int tt = t0 + wv;
#pragma unroll
    for (int ma = 0; ma < 4; ++ma) {
#pragma unroll
        for (int na = 0; na < 2; ++na) {
            const int v = na * 16 + r16;
            if (v < Vn) {
                const int ob = ma * 16 + g4 * 4;
#pragma unroll
                for (int r = 0; r < 4; ++r) {
                    const int o = ob + r;
                    const float xv = bf2f((unsigned short)xc[ma][na][r]);
                    float val = (accF[ma][na][r] + bnp[320 + o]) * bnp[192 + o] + bnp[256 + o];
                    float y2v = xv + val;
                    y2v = (y2v > 0.f) ? y2v : 0.1f * y2v;
                    float outv = y2v + xv;
                    outv = (outv > 0.f) ? outv : 0.f;
                    out[((size_t)(n * Cn + o) * Vn + v) * Tn + tt] = outv;
                }
            }
        }
    }
}

// ---------------------------------------------------------------------------
extern "C" void kernel_launch(void* const* d_in, const int* in_sizes, int n_in,
                              void* d_out, int out_size, void* d_ws, size_t ws_size,
                              hipStream_t stream) {
    const float* x       = (const float*)d_in[0];
    const float* graph   = (const float*)d_in[1];
    const float* graph_a = (const float*)d_in[2];
    const float* in_w    = (const float*)d_in[3];
    const float* in_b    = (const float*)d_in[4];
    const float* inup_w  = (const float*)d_in[5];
    const float* inup_b  = (const float*)d_in[6];
    const float* diff_w  = (const float*)d_in[7];
    const float* diff_b  = (const float*)d_in[8];
    const float* att0    = (const float*)d_in[9];
    const float* out_w   = (const float*)d_in[10];
    const float* out_b   = (const float*)d_in[11];
    const float* og      = (const float*)d_in[12];
    const float* obeta   = (const float*)d_in[13];
    const float* orm     = (const float*)d_in[14];
    const float* orv     = (const float*)d_in[15];
    const float* ff_w    = (const float*)d_in[16];
    const float* ff_b    = (const float*)d_in[17];
    const float* fg      = (const float*)d_in[18];
    const float* fbeta   = (const float*)d_in[19];
    const float* frm     = (const float*)d_in[20];
    const float* frv     = (const float*)d_in[21];
    float* out = (float*)d_out;

    // ws layout (bytes): red@0 (64K) | gate@65,536 | attB@71,680 (3M)
    //   out_wbf@3,217,408 | ff_wbf@3,282,944 | pq@3,291,136 | pk@16,398,336
    char* wsb = (char*)d_ws;
    float* red_ws  = (float*)(wsb);
    float* gate_ws = (float*)(wsb + 65536);
    unsigned short* attB = (unsigned short*)(wsb + 71680);
    unsigned short* owb  = (unsigned short*)(wsb + 3217408);
    unsigned short* fwb  = (unsigned short*)(wsb + 3282944);
    unsigned short* pq = (unsigned short*)(wsb + 3291136);
    unsigned short* pk = (unsigned short*)(wsb + 16398336);

    k_red<<<dim3(Cn, Nn), 64, 0, stream>>>(x, graph_a, red_ws);
    k_gate<<<dim3(Nn), 64, 0, stream>>>(red_ws, diff_w, diff_b, gate_ws);
    k_conv<<<dim3(128), 256, 0, stream>>>(out_w, ff_w, owb, fwb);
    k_proj<<<dim3(Vn, Nn), 256, 0, stream>>>(x, in_w, in_b, inup_w, inup_b, pk, pq);
    k_att3<<<dim3(Nn, Sn), 256, 0, stream>>>(pq, pk, inup_b, graph, att0, gate_ws, attB);
    k_main6<<<dim3(Nn, Tn / 4), 256, 0, stream>>>(x, attB, owb, out_b, og, obeta,
                                                  orm, orv, fwb, ff_b, fg, fbeta,
                                                  frm, frv, out);
}

// Round 8
// 155.579 us; speedup vs baseline: 1.2325x; 1.1356x over previous
//
#include <hip/hip_runtime.h>
#include <hip/hip_bf16.h>
#include <math.h>

#define Nn 64
#define Cn 64
#define Tn 64
#define Vn 25
#define Sn 8
#define ICn 8
#define Wn 3
#define WVn 75

typedef __attribute__((ext_vector_type(8))) short s16x8;   // 8 bf16 (4 VGPR)
typedef __attribute__((ext_vector_type(4))) short s16x4;   // 4 bf16 (2 VGPR)
typedef __attribute__((ext_vector_type(4))) float f32x4;   // MFMA acc

#define MFMA16(a, b, c) __builtin_amdgcn_mfma_f32_16x16x32_bf16(a, b, c, 0, 0, 0)

static __device__ inline unsigned short f2bf(float f) {
    __hip_bfloat16 h = __float2bfloat16(f);
    return *reinterpret_cast<unsigned short*>(&h);
}
static __device__ inline float bf2f(unsigned short u) {
    union { unsigned int i; float f; } x;
    x.i = ((unsigned int)u) << 16;
    return x.f;
}

// ---------------------------------------------------------------------------
// K1: per (n,c) reductions over x rows (collapsed diff/gate branch).
// ---------------------------------------------------------------------------
__global__ __launch_bounds__(64) void k_red(const float* __restrict__ x,
                                            const float* __restrict__ ga,
                                            float* __restrict__ red) {
    const int c = blockIdx.x, n = blockIdx.y;
    const int lane = threadIdx.x;
    float rs = 0.f, r0 = 0.f, r63 = 0.f, xg = 0.f;
    if (lane < Vn) {
        const float* row = x + ((size_t)(n * Cn + c) * Vn + lane) * Tn;
        float g = 0.f;
        for (int j = 0; j < Vn; ++j) g += ga[lane * Vn + j];
        for (int t = 0; t < Tn; ++t) rs += row[t];
        r0 = row[0];
        r63 = row[Tn - 1];
        xg = rs * g;
    }
    for (int off = 32; off > 0; off >>= 1) {
        rs += __shfl_down(rs, off);
        r0 += __shfl_down(r0, off);
        r63 += __shfl_down(r63, off);
        xg += __shfl_down(xg, off);
    }
    if (lane == 0) {
        float* p = red + (size_t)(n * Cn + c) * 4;
        p[0] = rs; p[1] = r0; p[2] = r63; p[3] = xg;
    }
}

// ---------------------------------------------------------------------------
// K1b: gate[n,s,w]
// ---------------------------------------------------------------------------
__global__ __launch_bounds__(64) void k_gate(const float* __restrict__ red,
                                             const float* __restrict__ diff_w,
                                             const float* __restrict__ diff_b,
                                             float* __restrict__ gate) {
    const int n = blockIdx.x;
    const int s = threadIdx.x;
    if (s >= Sn) return;
    float sumd2 = 0.f, rsum = 0.f, rr0 = 0.f, rr63 = 0.f;
    for (int cc = 0; cc < ICn; ++cc) {
        const int oc = s * ICn + cc;
        float a = 0.f;
        for (int c = 0; c < Cn; ++c)
            a += red[(n * Cn + c) * 4 + 3] * diff_w[oc * Cn + c];
        sumd2 += a + 1600.f * diff_b[oc];
        rsum += red[(n * Cn + oc) * 4 + 0];
        rr0  += red[(n * Cn + oc) * 4 + 1];
        rr63 += red[(n * Cn + oc) * 4 + 2];
    }
    const float inv = 1.f / 12800.f;
    float m0 = (sumd2 - (rsum - rr63)) * inv;
    float m1 = (sumd2 - rsum) * inv;
    float m2 = (sumd2 - (rsum - rr0)) * inv;
    float* gp = gate + (n * Sn + s) * Wn;
    gp[0] = 1.f / (1.f + expf(-m0));
    gp[1] = 1.f / (1.f + expf(-m1));
    gp[2] = 1.f / (1.f + expf(-m2));
}

// ---------------------------------------------------------------------------
// K_conv: out_w / ff_w -> bf16
// ---------------------------------------------------------------------------
__global__ __launch_bounds__(256) void k_conv(const float* __restrict__ ow,
                                              const float* __restrict__ fw,
                                              unsigned short* __restrict__ owb,
                                              unsigned short* __restrict__ fwb) {
    int i = blockIdx.x * 256 + threadIdx.x;
    if (i < 64 * 512) owb[i] = f2bf(ow[i]);
    if (i < 64 * 64)  fwb[i] = f2bf(fw[i]);
}

// ---------------------------------------------------------------------------
// K_proj: q/k conv1x1 projections -> bf16, layout [n][v][t][o] (o fastest).
// ---------------------------------------------------------------------------
__global__ __launch_bounds__(256) void k_proj(
    const float* __restrict__ x,
    const float* __restrict__ in_w, const float* __restrict__ in_b,
    const float* __restrict__ inup_w, const float* __restrict__ inup_b,
    unsigned short* __restrict__ pk, unsigned short* __restrict__ pq) {
    const int v = blockIdx.x, n = blockIdx.y;
    const int tid = threadIdx.x;
    __shared__ float xs[64 * 65];   // [c][t]
    __shared__ float wk[64 * 65];   // [o][c]
    __shared__ float wq[64 * 65];

    for (int i = tid; i < 4096; i += 256) {
        int o = i >> 6, c = i & 63;
        wk[o * 65 + c] = in_w[i];
        wq[o * 65 + c] = inup_w[i];
    }
    for (int i = tid; i < 4096; i += 256) {
        int c = i >> 6, t = i & 63;
        xs[c * 65 + t] = x[((size_t)(n * Cn + c) * Vn + v) * Tn + t];
    }
    __syncthreads();

    const int o = tid & 63, tq = tid >> 6;   // wave-uniform tq
    float ak[16], aq[16];
#pragma unroll
    for (int t = 0; t < 16; ++t) { ak[t] = 0.f; aq[t] = 0.f; }
    for (int c = 0; c < 64; ++c) {
        float wkc = wk[o * 65 + c], wqc = wq[o * 65 + c];
        const float* xr = &xs[c * 65 + tq * 16];   // uniform address
#pragma unroll
        for (int t = 0; t < 16; ++t) {
            float xv = xr[t];
            ak[t] += wkc * xv;
            aq[t] += wqc * xv;
        }
    }
    const float bk = in_b[o], bq = inup_b[o];
    const size_t base = ((size_t)(n * Vn + v) * Tn + tq * 16) * 64 + o;
#pragma unroll
    for (int t = 0; t < 16; ++t) {
        pk[base + t * 64] = f2bf(ak[t] + bk);
        pq[base + t * 64] = f2bf(aq[t] + bq);
    }
}

// ---------------------------------------------------------------------------
// K_att3 (MFMA): fused attention logits + softmax + gate + att0 -> attB.
// ---------------------------------------------------------------------------
__global__ __launch_bounds__(256) void k_att3(
    const unsigned short* __restrict__ pq, const unsigned short* __restrict__ pk,
    const float* __restrict__ inup_b, const float* __restrict__ graph,
    const float* __restrict__ att0, const float* __restrict__ gate,
    unsigned short* __restrict__ attB) {
    const int n = blockIdx.x, s = blockIdx.y;
    const int tid = threadIdx.x;
    const int lane = tid & 63, wv = tid >> 6;
    const int r16 = lane & 15, g4 = lane >> 4;

    __shared__ unsigned short QS[25 * 536];   // [uu][slot 0..66][cc]
    __shared__ unsigned short KS[32 * 512];   // [v][(t^(v&7))*8+cc]
    __shared__ float attL[80 * 33];

    for (int i = tid; i < 2048; i += 256) {
        const int t = i & 63, v = i >> 6;
        s16x8 d = (s16x8){0, 0, 0, 0, 0, 0, 0, 0};
        if (v < Vn)
            d = *(const s16x8*)(pk + (((size_t)(n * Vn + v) * Tn + t) << 6) + s * ICn);
        *(s16x8*)&KS[v * 512 + ((t ^ (v & 7)) << 3)] = d;
    }
    for (int i = tid; i < 1600; i += 256) {
        const int t = i & 63, uu = i >> 6;
        const s16x8 d = *(const s16x8*)(pq +
            (((size_t)(n * Vn + uu) * Tn + t) << 6) + s * ICn);
        *(s16x8*)&QS[uu * 536 + (t + 1) * 8] = d;
    }
    if (tid < 50) {  // bias edge slots 0 and 65
        const int uu = tid >> 1, slot = (tid & 1) * 65;
#pragma unroll
        for (int cc = 0; cc < ICn; ++cc)
            QS[uu * 536 + slot * 8 + cc] = f2bf(inup_b[s * ICn + cc]);
    }
    __syncthreads();

    for (int tile = wv; tile < 10; tile += 4) {
        const int mt = tile >> 1, nt = tile & 1;
        const int u = mt * 16 + r16;
        const int w = u / 25, uu = u % 25;
        const int v = nt * 16 + r16;
        const unsigned short* qbase = &QS[uu * 536 + (g4 + w) * 8];
        const unsigned short* kbase = &KS[v * 512];
        f32x4 acc = (f32x4){0.f, 0.f, 0.f, 0.f};
#pragma unroll
        for (int kb = 0; kb < 16; ++kb) {
            const s16x8 af = *(const s16x8*)(qbase + kb * 32);
            const s16x8 bf = *(const s16x8*)(kbase + (((kb * 4 + g4) ^ (v & 7)) << 3));
            acc = MFMA16(af, bf, acc);
        }
#pragma unroll
        for (int r = 0; r < 4; ++r)
            attL[(mt * 16 + g4 * 4 + r) * 33 + v] = acc[r];
    }
    __syncthreads();

    if (tid < WVn) {
        const int u = tid, u0 = u % Vn;
        const float* gr = graph + (s * Vn + u0) * Vn;
        float av[Vn];
        float mx = -1e30f;
#pragma unroll
        for (int v = 0; v < Vn; ++v) {
            float a = attL[u * 33 + v] * (1.f / 512.f);
            av[v] = (gr[v] > 0.f) ? a : -1e30f;
            mx = fmaxf(mx, av[v]);
        }
        float ssum = 0.f;
#pragma unroll
        for (int v = 0; v < Vn; ++v) {
            float e = (av[v] > -1e29f) ? expf(av[v] - mx) : 0.f;
            av[v] = e;
            ssum += e;
        }
        const float g = gate[(n * Sn + s) * Wn + (u % Wn)];
        const float sc = g / ssum;
        const float* a0 = att0 + (s * WVn + u) * Vn;
#pragma unroll
        for (int v = 0; v < Vn; ++v) attL[u * 33 + v] = av[v] * sc + a0[v];
    }
    __syncthreads();

    unsigned short* ab = attB + ((size_t)(n * Sn + s)) * 32 * 96;
    for (int i = tid; i < 32 * 96; i += 256) {
        const int v = i / 96, kk = i % 96;
        const int w2 = kk >> 5, vp = kk & 31;
        float val = (v < Vn && vp < Vn) ? attL[(w2 * Vn + vp) * 33 + v] : 0.f;
        ab[i] = f2bf(val);
    }
}

// ---------------------------------------------------------------------------
// K_trans: x (N,C,V,T fp32) -> xT[n][t][c][v-swz] bf16.
// Per (c)-row of 32 v = 4 chunks of 8; chunk position p holds v-range
// ((p ^ (c&3))*8 .. +8), v>=25 zeroed. So a per-(n,t) slab is 4KB contiguous
// and A-frag b128 reads at chunk (g4 ^ (c&3)) get v-range g4*8 conflict-lite.
// ---------------------------------------------------------------------------
__global__ __launch_bounds__(256) void k_trans(const float* __restrict__ x,
                                               unsigned short* __restrict__ xT) {
    const int n = blockIdx.x, cb = blockIdx.y;  // 16 chunks of 4 c
    const int c0 = cb * 4;
    const int tid = threadIdx.x;
    __shared__ unsigned short XL[4][25][66];    // [cl][v][t] pad 66

    for (int i = tid; i < 1600; i += 256) {
        const int piece = i & 15, row = i >> 4;     // row = cl*25 + v
        const int cl = row / 25, v = row - cl * 25;
        const float4 d = *(const float4*)(x +
            ((size_t)((n * Cn + c0 + cl) * Vn + v)) * Tn + piece * 4);
        unsigned short* dst = &XL[cl][v][piece * 4];
        dst[0] = f2bf(d.x); dst[1] = f2bf(d.y); dst[2] = f2bf(d.z); dst[3] = f2bf(d.w);
    }
    __syncthreads();
    for (int j = tid; j < 1024; j += 256) {     // 64t x 4cl x 4 chunks
        const int p = j & 3, cl = (j >> 2) & 3, t = j >> 4;
        const int v0 = (p ^ cl) * 8;
        unsigned short buf[8];
#pragma unroll
        for (int jj = 0; jj < 8; ++jj) {
            const int v = v0 + jj;
            buf[jj] = (v < Vn) ? XL[cl][v][t] : (unsigned short)0;
        }
        *(s16x8*)(xT + ((size_t)(n * Tn + t) * 2048) + (c0 + cl) * 32 + p * 8) =
            *(const s16x8*)buf;
    }
}

// ---------------------------------------------------------------------------
// K_main7: block = one (n,t), 4 waves, 3 blocks/CU.
//   stage: xs3 = xT rows t-1,t,t+1 (4KB each, coalesced; OOB -> zeros)
//   phase1: wave wv aggregates s = 2wv, 2wv+1:
//     y2[s][c][v] = sum_u upf[c,u] att[s][u][v]  (48 MFMA) -> y2L[v][(s,c)]
//   phase2: K=512 GEMM  accO[o][v] = out_w[o,(s,c)] * y2L   (32 MFMA/wave)
//   epi1 -> y1L[v][o];  ff K=64;  epi2 -> out.
// y2L/y1L chunk-XOR swizzled by (v&7) -> 2-way banked b128 reads.
// ---------------------------------------------------------------------------
__global__ __launch_bounds__(256, 3) void k_main7(
    const unsigned short* __restrict__ xT, const unsigned short* __restrict__ attB,
    const unsigned short* __restrict__ out_wbf, const float* __restrict__ out_b,
    const float* __restrict__ og, const float* __restrict__ obeta,
    const float* __restrict__ orm, const float* __restrict__ orv,
    const unsigned short* __restrict__ ff_wbf, const float* __restrict__ ff_b,
    const float* __restrict__ fg, const float* __restrict__ fbeta,
    const float* __restrict__ frm, const float* __restrict__ frv,
    float* __restrict__ out) {
    const int n = blockIdx.x, t = blockIdx.y;
    const int tid = threadIdx.x;
    const int lane = tid & 63, wv = tid >> 6;
    const int r16 = lane & 15, g4 = lane >> 4;

    __shared__ unsigned short xs3[3 * 2048];   // 12 KB
    __shared__ unsigned short y2L[32 * 512];   // 32 KB
    __shared__ unsigned short y1L[32 * 64];    // 4 KB
    __shared__ float bnp[384];

    if (tid < 64) {
        int o = tid;
        float so = og[o] * rsqrtf(orv[o] + 1e-5f);
        bnp[o] = so; bnp[64 + o] = obeta[o] - orm[o] * so; bnp[128 + o] = out_b[o];
        float sf = fg[o] * rsqrtf(frv[o] + 1e-5f);
        bnp[192 + o] = sf; bnp[256 + o] = fbeta[o] - frm[o] * sf; bnp[320 + o] = ff_b[o];
    }
    // ---- stage xs3 (768 x 16B chunks, coalesced)
    for (int ch = tid; ch < 768; ch += 256) {
        const int kb = ch >> 8, off = ch & 255;
        const int tg = t - 1 + kb;
        s16x8 d = (s16x8){0, 0, 0, 0, 0, 0, 0, 0};
        if (tg >= 0 && tg < Tn)
            d = *(const s16x8*)(xT + ((size_t)(n * Tn + tg) * 2048) + off * 8);
        *(s16x8*)&xs3[ch * 8] = d;
    }
    __syncthreads();

    // ---- phase1: aggregation (wave-private s pair)
    s16x8 af[4][3];
#pragma unroll
    for (int m = 0; m < 4; ++m) {
        const int c = m * 16 + r16;
#pragma unroll
        for (int kb = 0; kb < 3; ++kb)
            af[m][kb] = *(const s16x8*)&xs3[kb * 2048 + c * 32 + ((g4 ^ (c & 3)) << 3)];
    }
#pragma unroll
    for (int si = 0; si < 2; ++si) {
        const int s = wv * 2 + si;
        const unsigned short* aB = attB + ((size_t)(n * Sn + s)) * 32 * 96;
        s16x8 bfr[3][2];
#pragma unroll
        for (int k = 0; k < 3; ++k)
#pragma unroll
            for (int nt = 0; nt < 2; ++nt)
                bfr[k][nt] = *(const s16x8*)(aB + (nt * 16 + r16) * 96 + k * 32 + g4 * 8);
#pragma unroll
        for (int m = 0; m < 4; ++m) {
            f32x4 c0 = (f32x4){0.f, 0.f, 0.f, 0.f};
            f32x4 c1 = (f32x4){0.f, 0.f, 0.f, 0.f};
#pragma unroll
            for (int kb = 0; kb < 3; ++kb) {
                c0 = MFMA16(af[m][kb], bfr[kb][0], c0);
                c1 = MFMA16(af[m][kb], bfr[kb][1], c1);
            }
            const int cw = m * 16 + g4 * 4;
            s16x4 p0, p1;
#pragma unroll
            for (int r = 0; r < 4; ++r) { p0[r] = f2bf(c0[r]); p1[r] = f2bf(c1[r]); }
            const int v0 = r16, v1 = 16 + r16;
            *(s16x4*)&y2L[v0 * 512 + (s * 8 + ((cw >> 3) ^ (v0 & 7))) * 8 + (cw & 7)] = p0;
            *(s16x4*)&y2L[v1 * 512 + (s * 8 + ((cw >> 3) ^ (v1 & 7))) * 8 + (cw & 7)] = p1;
        }
    }
    __syncthreads();

    // ---- phase2: out-proj GEMM K=512
    f32x4 accO[2];
    accO[0] = (f32x4){0.f, 0.f, 0.f, 0.f};
    accO[1] = (f32x4){0.f, 0.f, 0.f, 0.f};
    const int orow = wv * 16 + r16;
#pragma unroll
    for (int ks = 0; ks < 16; ++ks) {
        const s16x8 wa = *(const s16x8*)(out_wbf + (size_t)orow * 512 + ks * 32 + g4 * 8);
        const int cidx = ks * 4 + g4;            // k-chunk 0..63
        const int srow = cidx >> 3, lc = cidx & 7;
#pragma unroll
        for (int na = 0; na < 2; ++na) {
            const int v = na * 16 + r16;
            const s16x8 b = *(const s16x8*)&y2L[v * 512 + (srow * 8 + (lc ^ (v & 7))) * 8];
            accO[na] = MFMA16(wa, b, accO[na]);
        }
    }
    // ---- epi1: y1 = leaky(x + BN(accO)) -> y1L[v][o], cache xv
    float xvc[2][4];
    const int ob = wv * 16 + g4 * 4;
#pragma unroll
    for (int na = 0; na < 2; ++na) {
        const int v = na * 16 + r16;
        s16x4 p;
#pragma unroll
        for (int r = 0; r < 4; ++r) {
            const int o = ob + r;
            const float xv = bf2f(xs3[2048 + o * 32 + ((((v >> 3)) ^ (o & 3)) << 3) + (v & 7)]);
            xvc[na][r] = xv;
            float val = (accO[na][r] + bnp[128 + o]) * bnp[o] + bnp[64 + o];
            float y1 = xv + val;
            y1 = (y1 > 0.f) ? y1 : 0.1f * y1;
            p[r] = f2bf(y1);
        }
        *(s16x4*)&y1L[v * 64 + (((ob >> 3) ^ (v & 7)) << 3) + (ob & 7)] = p;
    }
    __syncthreads();

    // ---- ff: K=64 GEMM
    f32x4 accF[2];
    accF[0] = (f32x4){0.f, 0.f, 0.f, 0.f};
    accF[1] = (f32x4){0.f, 0.f, 0.f, 0.f};
#pragma unroll
    for (int ks = 0; ks < 2; ++ks) {
        const s16x8 fa = *(const s16x8*)(ff_wbf + (size_t)orow * 64 + ks * 32 + g4 * 8);
        const int cidx = ks * 4 + g4;            // o-chunk 0..7
#pragma unroll
        for (int na = 0; na < 2; ++na) {
            const int v = na * 16 + r16;
            const s16x8 b = *(const s16x8*)&y1L[v * 64 + ((cidx ^ (v & 7)) << 3)];
            accF[na] = MFMA16(fa, b, accF[na]);
        }
    }
    // ---- epi2 + store
#pragma unroll
    for (int na = 0; na < 2; ++na) {
        const int v = na * 16 + r16;
        if (v < Vn) {
#pragma unroll
            for (int r = 0; r < 4; ++r) {
                const int o = ob + r;
                const float xv = xvc[na][r];
                float val = (accF[na][r] + bnp[320 + o]) * bnp[192 + o] + bnp[256 + o];
                float y2v = xv + val;
                y2v = (y2v > 0.f) ? y2v : 0.1f * y2v;
                float outv = y2v + xv;
                outv = (outv > 0.f) ? outv : 0.f;
                out[((size_t)(n * Cn + o) * Vn + v) * Tn + t] = outv;
            }
        }
    }
}

// ---------------------------------------------------------------------------
extern "C" void kernel_launch(void* const* d_in, const int* in_sizes, int n_in,
                              void* d_out, int out_size, void* d_ws, size_t ws_size,
                              hipStream_t stream) {
    const float* x       = (const float*)d_in[0];
    const float* graph   = (const float*)d_in[1];
    const float* graph_a = (const float*)d_in[2];
    const float* in_w    = (const float*)d_in[3];
    const float* in_b    = (const float*)d_in[4];
    const float* inup_w  = (const float*)d_in[5];
    const float* inup_b  = (const float*)d_in[6];
    const float* diff_w  = (const float*)d_in[7];
    const float* diff_b  = (const float*)d_in[8];
    const float* att0    = (const float*)d_in[9];
    const float* out_w   = (const float*)d_in[10];
    const float* out_b   = (const float*)d_in[11];
    const float* og      = (const float*)d_in[12];
    const float* obeta   = (const float*)d_in[13];
    const float* orm     = (const float*)d_in[14];
    const float* orv     = (const float*)d_in[15];
    const float* ff_w    = (const float*)d_in[16];
    const float* ff_b    = (const float*)d_in[17];
    const float* fg      = (const float*)d_in[18];
    const float* fbeta   = (const float*)d_in[19];
    const float* frm     = (const float*)d_in[20];
    const float* frv     = (const float*)d_in[21];
    float* out = (float*)d_out;

    // ws layout (bytes): red@0 (64K) | gate@65,536 | attB@71,680 (3M)
    //   out_wbf@3,217,408 | ff_wbf@3,282,944 | pq@3,291,136 | pk@16,398,336
    //   xT ALIASES pq/pk (dead after k_att3; k_trans launched after it):
    //   xT@3,291,136 (16,777,216 B)
    char* wsb = (char*)d_ws;
    float* red_ws  = (float*)(wsb);
    float* gate_ws = (float*)(wsb + 65536);
    unsigned short* attB = (unsigned short*)(wsb + 71680);
    unsigned short* owb  = (unsigned short*)(wsb + 3217408);
    unsigned short* fwb  = (unsigned short*)(wsb + 3282944);
    unsigned short* pq = (unsigned short*)(wsb + 3291136);
    unsigned short* pk = (unsigned short*)(wsb + 16398336);
    unsigned short* xT = (unsigned short*)(wsb + 3291136);

    k_red<<<dim3(Cn, Nn), 64, 0, stream>>>(x, graph_a, red_ws);
    k_gate<<<dim3(Nn), 64, 0, stream>>>(red_ws, diff_w, diff_b, gate_ws);
    k_conv<<<dim3(128), 256, 0, stream>>>(out_w, ff_w, owb, fwb);
    k_proj<<<dim3(Vn, Nn), 256, 0, stream>>>(x, in_w, in_b, inup_w, inup_b, pk, pq);
    k_att3<<<dim3(Nn, Sn), 256, 0, stream>>>(pq, pk, inup_b, graph, att0, gate_ws, attB);
    k_trans<<<dim3(Nn, 16), 256, 0, stream>>>(x, xT);
    k_main7<<<dim3(Nn, Tn), 256, 0, stream>>>(xT, attB, owb, out_b, og, obeta,
                                              orm, orv, fwb, ff_b, fg, fbeta,
                                              frm, frv, out);
}